// Round 4
// baseline (123.354 us; speedup 1.0000x reference)
//
#include <hip/hip_runtime.h>

typedef unsigned short u16;
typedef __attribute__((ext_vector_type(8))) short short8;
typedef __attribute__((ext_vector_type(4))) float f32x4;

#define GL2LDS16(src, dst) __builtin_amdgcn_global_load_lds( \
    (const __attribute__((address_space(1))) void*)(src),    \
    (__attribute__((address_space(3))) void*)(dst), 16, 0, 0)

__device__ __forceinline__ u16 f2bf(float f) {
  union { float f; unsigned u; } v; v.f = f;
  unsigned r = v.u + 0x7fffu + ((v.u >> 16) & 1u);
  return (u16)(r >> 16);
}
__device__ __forceinline__ float bf2f(u16 h) {
  union { unsigned u; float f; } v; v.u = ((unsigned)h) << 16; return v.f;
}

// ---------------- gates + x->bf16 conversion, one wave per row ----------------
__global__ void k_gates_cvt(const float* __restrict__ xf, const float* __restrict__ x1,
                            const float* __restrict__ x2,
                            const float* __restrict__ gshW, const float* __restrict__ gshB,
                            const float* __restrict__ g1W, const float* __restrict__ g1B,
                            const float* __restrict__ g2W, const float* __restrict__ g2B,
                            u16* __restrict__ xfb, u16* __restrict__ x1b, u16* __restrict__ x2b,
                            float* __restrict__ gsh, float* __restrict__ g1o,
                            float* __restrict__ g2o) {
  const int b = blockIdx.x, lane = threadIdx.x;
  float s[12];
#pragma unroll
  for (int j = 0; j < 12; ++j) s[j] = 0.f;
  {
    const float* xr = xf + (size_t)b * 1024;
    u16* xw = xfb + (size_t)b * 1024;
    for (int k = lane; k < 1024; k += 64) {
      float v = xr[k];
      xw[k] = f2bf(v);
      const float* wr = gshW + (size_t)k * 12;
#pragma unroll
      for (int j = 0; j < 12; ++j) s[j] += v * wr[j];
    }
  }
  float u[8], w[8];
#pragma unroll
  for (int j = 0; j < 8; ++j) { u[j] = 0.f; w[j] = 0.f; }
  {
    const float* xr1 = x1 + (size_t)b * 512;
    const float* xr2 = x2 + (size_t)b * 512;
    u16* xw1 = x1b + (size_t)b * 512;
    u16* xw2 = x2b + (size_t)b * 512;
    for (int k = lane; k < 512; k += 64) {
      float v1 = xr1[k], v2 = xr2[k];
      xw1[k] = f2bf(v1); xw2[k] = f2bf(v2);
      const float* w1r = g1W + (size_t)k * 8;
      const float* w2r = g2W + (size_t)k * 8;
#pragma unroll
      for (int j = 0; j < 8; ++j) { u[j] += v1 * w1r[j]; w[j] += v2 * w2r[j]; }
    }
  }
#pragma unroll
  for (int off = 32; off >= 1; off >>= 1) {
#pragma unroll
    for (int j = 0; j < 12; ++j) s[j] += __shfl_xor(s[j], off, 64);
#pragma unroll
    for (int j = 0; j < 8; ++j) { u[j] += __shfl_xor(u[j], off, 64); w[j] += __shfl_xor(w[j], off, 64); }
  }
  if (lane == 0) {
    float m = -1e30f, tot = 0.f;
#pragma unroll
    for (int j = 0; j < 12; ++j) { s[j] += gshB[j]; m = fmaxf(m, s[j]); }
#pragma unroll
    for (int j = 0; j < 12; ++j) { s[j] = __expf(s[j] - m); tot += s[j]; }
    float inv = 1.f / tot;
#pragma unroll
    for (int j = 0; j < 12; ++j) gsh[(size_t)b * 12 + j] = s[j] * inv;
    m = -1e30f; tot = 0.f;
#pragma unroll
    for (int j = 0; j < 8; ++j) { u[j] += g1B[j]; m = fmaxf(m, u[j]); }
#pragma unroll
    for (int j = 0; j < 8; ++j) { u[j] = __expf(u[j] - m); tot += u[j]; }
    inv = 1.f / tot;
#pragma unroll
    for (int j = 0; j < 8; ++j) g1o[(size_t)b * 8 + j] = u[j] * inv;
    m = -1e30f; tot = 0.f;
#pragma unroll
    for (int j = 0; j < 8; ++j) { w[j] += g2B[j]; m = fmaxf(m, w[j]); }
#pragma unroll
    for (int j = 0; j < 8; ++j) { w[j] = __expf(w[j] - m); tot += w[j]; }
    inv = 1.f / tot;
#pragma unroll
    for (int j = 0; j < 8; ++j) g2o[(size_t)b * 8 + j] = w[j] * inv;
  }
}

// ------------- merged weight transpose+convert: fp32 [z][R][C] -> bf16 [z][C][R] -------------
struct TD { const float* src; u16* dst; int lgTps; int lgNtx; int R; int C; int tileBase; };
struct TArgs { TD d[6]; };

__global__ void k_transpose_all(TArgs ta) {
  __shared__ float tile[32][33];
  const int x = blockIdx.x;
  int di = 0;
#pragma unroll
  for (int i = 1; i < 6; ++i)
    if (x >= ta.d[i].tileBase) di = i;
  TD d = ta.d[di];
  const int local = x - d.tileBase;
  const int slice = local >> d.lgTps;
  const int ti = local & ((1 << d.lgTps) - 1);
  const int tx = ti & ((1 << d.lgNtx) - 1);
  const int ty = ti >> d.lgNtx;
  const float* src = d.src + (size_t)slice * d.R * d.C;
  u16* dst = d.dst + (size_t)slice * d.R * d.C;
  const int c0 = tx * 32, r0 = ty * 32;
  const int ttx = threadIdx.x, tty = threadIdx.y;
#pragma unroll
  for (int i = tty; i < 32; i += 8)
    tile[i][ttx] = src[(size_t)(r0 + i) * d.C + (c0 + ttx)];
  __syncthreads();
#pragma unroll
  for (int i = tty; i < 32; i += 8)
    dst[(size_t)(c0 + i) * d.R + (r0 + ttx)] = f2bf(tile[ttx][i]);
}

// ------------- flipped grouped 256x256 8-phase GEMM: Ct = relu(W @ X^T + bias)^T -------------
// W: [M][K] bf16 (weights, M=512 or 256); X: [4096][K] bf16 (batch); Ct: [4096][M] bf16.
// BM=BN=256, BK=64, 8 waves (2M x 4N), wave tile 128x64, acc[8][4].
// 8 phases / 2 K-tiles with cross-phase read pre-issue + counted lgkmcnt.
// LDS: A 2buf x 2half x [128][64]; B 2buf x 2ksub x [256][32]. 128 KiB.
// Swizzle (both-sides): A chunk^=(r&7); B chunk^=((r>>1)&3). Measured 0 conflicts.
struct GemmDesc {
  const u16* W;
  const u16* X;
  const float* bias;
  u16* Ct;
  int K;
  int M;
  int iters;  // K/128
};
struct GemmArgs { GemmDesc d[12]; };

#define LDA4(DST, BUF, KS, MH)                                                  \
  _Pragma("unroll") for (int q = 0; q < 4; ++q)                                 \
      DST[q] = *(const short8*)((const char*)As + (BUF) * 32768 +               \
                                (aoff[(MH) * 4 + q] ^ ((KS) * 64)));

#define LDB4(DST, BUF, KS)                                                      \
  _Pragma("unroll") for (int n = 0; n < 4; ++n)                                 \
      DST[n] = *(const short8*)((const char*)Bs + (BUF) * 32768 +               \
                                (KS) * 16384 + boff[n]);

#define MFMA16(AF, BF, MH)                                                      \
  __builtin_amdgcn_s_setprio(1);                                                \
  _Pragma("unroll") for (int q = 0; q < 4; ++q)                                 \
      _Pragma("unroll") for (int n = 0; n < 4; ++n)                             \
          acc[(MH) * 4 + q][n] = __builtin_amdgcn_mfma_f32_16x16x32_bf16(       \
              AF[q], BF[n], acc[(MH) * 4 + q][n], 0, 0, 0);                     \
  __builtin_amdgcn_s_setprio(0);

#define BARR __builtin_amdgcn_s_barrier()
#define WAITL(N)                                                 \
  {                                                              \
    asm volatile("s_waitcnt lgkmcnt(" #N ")" ::: "memory");      \
    __builtin_amdgcn_sched_barrier(0);                           \
  }
#define WAITV(N) asm volatile("s_waitcnt vmcnt(" #N ")" ::: "memory")

__global__ __launch_bounds__(512, 1) void k_gemm256(GemmArgs args) {
  __shared__ __align__(16) u16 As[32768];  // 2buf x 2half x 128 x 64
  __shared__ __align__(16) u16 Bs[32768];  // 2buf x 2ksub x 256 x 32

  GemmDesc g = args.d[blockIdx.y];
  const int K = g.K, M = g.M, iters = g.iters;
  const int bx = blockIdx.x;
  const int row0 = (bx >> 4) << 8;   // M-tile (0..ntM-1)
  const int col0 = (bx & 15) << 8;   // batch-tile (16 of 4096/256)

  const int tid = threadIdx.x;
  const int lane = tid & 63;
  const int wid = tid >> 6;
  const int wm = wid & 1;    // 2 M-strips of 128
  const int wn = wid >> 1;   // 4 N-strips of 64
  const int lrow = lane & 15;
  const int lkq = lane >> 4;  // 0..3

  int aoff[8], boff[4];
#pragma unroll
  for (int mi = 0; mi < 8; ++mi)
    aoff[mi] = wm * 16384 + (mi * 16 + lrow) * 128 + ((lkq ^ (lrow & 7)) * 16);
#pragma unroll
  for (int ni = 0; ni < 4; ++ni)
    boff[ni] = (wn * 64 + ni * 16 + lrow) * 64 + ((lkq ^ ((lrow >> 1) & 3)) * 16);

  auto stageAhalf = [&](int buf, int half, int kt) {
#pragma unroll
    for (int j = 0; j < 2; ++j) {
      const int cb = (wid * 2 + j) * 64;
      const int c = cb + lane;
      const int r = c >> 3;
      const int cir = (c & 7) ^ (r & 7);
      GL2LDS16(g.W + (size_t)(row0 + half * 128 + r) * K + kt * 64 + cir * 8,
               &As[(buf * 2048 + half * 1024 + cb) * 8]);
    }
  };
  auto stageBhalf = [&](int buf, int ks, int kt) {
#pragma unroll
    for (int j = 0; j < 2; ++j) {
      const int cb = (wid * 2 + j) * 64;
      const int c = cb + lane;
      const int r = c >> 2;
      const int cir = (c & 3) ^ ((r >> 1) & 3);
      GL2LDS16(g.X + (size_t)(col0 + r) * K + kt * 64 + ks * 32 + cir * 8,
               &Bs[(buf * 2048 + ks * 1024 + cb) * 8]);
    }
  };

  f32x4 acc[8][4];
#pragma unroll
  for (int m = 0; m < 8; ++m)
#pragma unroll
    for (int n = 0; n < 4; ++n)
      acc[m][n] = (f32x4){0.f, 0.f, 0.f, 0.f};

  // prologue: buf0 <- tile 0 (B then A), buf1 <- tile 1 (B only)
  stageBhalf(0, 0, 0); stageBhalf(0, 1, 0);
  stageAhalf(0, 0, 0); stageAhalf(0, 1, 0);
  stageBhalf(1, 0, 1); stageBhalf(1, 1, 1);
  WAITV(4);
  BARR;

  short8 a_cur[4], a_nxt[4], b_cur[4], b_nxt[4];
  for (int i = 0; i < iters; ++i) {
    const int t1 = 2 * i + 1;
    const bool nl = (i + 1 < iters);
    // P1 (buf0,ks0,mh0) own reads + pre-issue P2's a
    LDB4(b_cur, 0, 0); LDA4(a_cur, 0, 0, 0); LDA4(a_nxt, 0, 0, 1);
    stageAhalf(1, 0, t1);
    BARR; WAITL(4); MFMA16(a_cur, b_cur, 0); BARR;
    // P2 (buf0,ks0,mh1); pre-issue P3's b,a
    LDB4(b_nxt, 0, 1); LDA4(a_cur, 0, 1, 0);
    stageAhalf(1, 1, t1);
    BARR; WAITL(8); MFMA16(a_nxt, b_cur, 1); BARR;
    // P3 (buf0,ks1,mh0); pre-issue P4's a
    LDA4(a_nxt, 0, 1, 1);
    if (nl) stageBhalf(0, 0, t1 + 1);
    BARR; WAITL(4); MFMA16(a_cur, b_nxt, 0); BARR;
    // P4 (buf0,ks1,mh1); crossing: no pre-issue
    if (nl) stageBhalf(0, 1, t1 + 1);
    BARR; WAITL(0); MFMA16(a_nxt, b_nxt, 1);
    if (nl) { WAITV(4); } else { WAITV(0); }
    BARR;
    // P5 (buf1,ks0,mh0) own + pre P6
    LDB4(b_cur, 1, 0); LDA4(a_cur, 1, 0, 0); LDA4(a_nxt, 1, 0, 1);
    if (nl) stageAhalf(0, 0, t1 + 1);
    BARR; WAITL(4); MFMA16(a_cur, b_cur, 0); BARR;
    // P6; pre P7
    LDB4(b_nxt, 1, 1); LDA4(a_cur, 1, 1, 0);
    if (nl) stageAhalf(0, 1, t1 + 1);
    BARR; WAITL(8); MFMA16(a_nxt, b_cur, 1); BARR;
    // P7; pre P8
    LDA4(a_nxt, 1, 1, 1);
    if (nl) stageBhalf(1, 0, t1 + 2);
    BARR; WAITL(4); MFMA16(a_cur, b_nxt, 0); BARR;
    // P8; crossing: no pre-issue
    if (nl) stageBhalf(1, 1, t1 + 2);
    BARR; WAITL(0); MFMA16(a_nxt, b_nxt, 1);
    WAITV(4);
    BARR;
  }

  // epilogue: bias + relu + Ct store (per-lane j-contiguous -> 8B stores)
  // C/D map: col(batch)=lane&15, row(M)=lkq*4+j
#pragma unroll
  for (int mi = 0; mi < 8; ++mi) {
    const int gr = row0 + wm * 128 + mi * 16 + lkq * 4;
    const float4 bv = *(const float4*)(g.bias + gr);
#pragma unroll
    for (int ni = 0; ni < 4; ++ni) {
      const int gc = col0 + wn * 64 + ni * 16 + lrow;
      unsigned lo = (unsigned)f2bf(fmaxf(acc[mi][ni][0] + bv.x, 0.f)) |
                    ((unsigned)f2bf(fmaxf(acc[mi][ni][1] + bv.y, 0.f)) << 16);
      unsigned hi = (unsigned)f2bf(fmaxf(acc[mi][ni][2] + bv.z, 0.f)) |
                    ((unsigned)f2bf(fmaxf(acc[mi][ni][3] + bv.w, 0.f)) << 16);
      *(uint2*)(g.Ct + (size_t)gc * M + gr) = make_uint2(lo, hi);
    }
  }
}

// ---------------- gated reduce: 3 outputs from 12 expert outputs ----------------
__global__ void k_reduce(const u16* __restrict__ OutB, const float* __restrict__ gsh,
                         const float* __restrict__ g1, const float* __restrict__ g2,
                         float* __restrict__ out) {
  int t = blockIdx.x * 256 + threadIdx.x;
  int b = t >> 5;
  int c0 = (t & 31) << 3;
  float wsh[12], w1[8], w2[8];
#pragma unroll
  for (int j = 0; j < 12; ++j) wsh[j] = gsh[(size_t)b * 12 + j];
#pragma unroll
  for (int j = 0; j < 8; ++j) { w1[j] = g1[(size_t)b * 8 + j]; w2[j] = g2[(size_t)b * 8 + j]; }
  float ash[8] = {0, 0, 0, 0, 0, 0, 0, 0};
  float a1[8] = {0, 0, 0, 0, 0, 0, 0, 0};
  float a2[8] = {0, 0, 0, 0, 0, 0, 0, 0};
#pragma unroll
  for (int e = 0; e < 12; ++e) {
    short8 v = *(const short8*)&OutB[((size_t)e * 4096 + b) * 256 + c0];
    float f[8];
#pragma unroll
    for (int i = 0; i < 8; ++i) f[i] = bf2f((u16)v[i]);
#pragma unroll
    for (int i = 0; i < 8; ++i) ash[i] += wsh[e] * f[i];
    if (e < 4) {
#pragma unroll
      for (int i = 0; i < 8; ++i) a1[i] += w1[e] * f[i];
    } else if (e < 8) {
#pragma unroll
      for (int i = 0; i < 8; ++i) a2[i] += w2[e - 4] * f[i];
    } else {
#pragma unroll
      for (int i = 0; i < 8; ++i) a1[i] += w1[e - 4] * f[i];
#pragma unroll
      for (int i = 0; i < 8; ++i) a2[i] += w2[e - 4] * f[i];
    }
  }
  size_t base = (size_t)b * 256 + c0;
  float4* o;
  o = (float4*)(out + base);
  o[0] = make_float4(ash[0], ash[1], ash[2], ash[3]);
  o[1] = make_float4(ash[4], ash[5], ash[6], ash[7]);
  o = (float4*)(out + 4096ull * 256 + base);
  o[0] = make_float4(a1[0], a1[1], a1[2], a1[3]);
  o[1] = make_float4(a1[4], a1[5], a1[6], a1[7]);
  o = (float4*)(out + 2ull * 4096 * 256 + base);
  o[0] = make_float4(a2[0], a2[1], a2[2], a2[3]);
  o[1] = make_float4(a2[4], a2[5], a2[6], a2[7]);
}

extern "C" void kernel_launch(void* const* d_in, const int* in_sizes, int n_in,
                              void* d_out, int out_size, void* d_ws, size_t ws_size,
                              hipStream_t stream) {
  const float* x_full = (const float*)d_in[0];
  const float* x_t1 = (const float*)d_in[1];
  const float* x_t2 = (const float*)d_in[2];
  const float* sh_W1 = (const float*)d_in[3];
  const float* sh_b1 = (const float*)d_in[4];
  const float* sh_W2 = (const float*)d_in[5];
  const float* sh_b2 = (const float*)d_in[6];
  const float* t1_W1 = (const float*)d_in[7];
  const float* t1_b1 = (const float*)d_in[8];
  const float* t1_W2 = (const float*)d_in[9];
  const float* t1_b2 = (const float*)d_in[10];
  const float* t2_W1 = (const float*)d_in[11];
  const float* t2_b1 = (const float*)d_in[12];
  const float* t2_W2 = (const float*)d_in[13];
  const float* t2_b2 = (const float*)d_in[14];
  const float* gsh_W = (const float*)d_in[15];
  const float* gsh_b = (const float*)d_in[16];
  const float* g1_W = (const float*)d_in[17];
  const float* g1_b = (const float*)d_in[18];
  const float* g2_W = (const float*)d_in[19];
  const float* g2_b = (const float*)d_in[20];

  char* ws = (char*)d_ws;
  size_t off = 0;
  auto alloc = [&](size_t bytes) -> void* {
    void* p = ws + off;
    off += (bytes + 255) & ~(size_t)255;
    return p;
  };
  u16* xf_b = (u16*)alloc(4096ull * 1024 * 2);
  u16* x1_b = (u16*)alloc(4096ull * 512 * 2);
  u16* x2_b = (u16*)alloc(4096ull * 512 * 2);
  u16* w1t_t1 = (u16*)alloc(4ull * 512 * 512 * 2);   // [e][HID=512][K=512]
  u16* w1t_t2 = (u16*)alloc(4ull * 512 * 512 * 2);
  u16* w1t_sh = (u16*)alloc(4ull * 512 * 1024 * 2);  // [e][512][1024]
  u16* w2t = (u16*)alloc(12ull * 256 * 512 * 2);     // [slot][OUT=256][HID=512]
  u16* H = (u16*)alloc(12ull * 4096 * 512 * 2);      // hidden [slot][4096][512]
  u16* OutB = (u16*)alloc(12ull * 4096 * 256 * 2);   // expert outputs [slot][4096][256]
  float* gshv = (float*)alloc(4096ull * 12 * 4);
  float* g1v = (float*)alloc(4096ull * 8 * 4);
  float* g2v = (float*)alloc(4096ull * 8 * 4);

  // --- gates + x->bf16 (fused) ---
  k_gates_cvt<<<4096, 64, 0, stream>>>(x_full, x_t1, x_t2, gsh_W, gsh_b, g1_W, g1_b, g2_W, g2_b,
                                       xf_b, x1_b, x2_b, gshv, g1v, g2v);

  // --- weight transpose+convert, single launch ---
  TArgs ta;
  ta.d[0] = TD{t1_W1, w1t_t1, 8, 4, 512, 512, 0};
  ta.d[1] = TD{t2_W1, w1t_t2, 8, 4, 512, 512, 1024};
  ta.d[2] = TD{sh_W1, w1t_sh, 9, 4, 1024, 512, 2048};
  ta.d[3] = TD{t1_W2, w2t, 7, 3, 512, 256, 4096};
  ta.d[4] = TD{t2_W2, w2t + 4ull * 256 * 512, 7, 3, 512, 256, 4608};
  ta.d[5] = TD{sh_W2, w2t + 8ull * 256 * 512, 7, 3, 512, 256, 5120};
  k_transpose_all<<<5632, dim3(32, 8), 0, stream>>>(ta);

  // --- GEMM1 (flipped): H[b][h] = relu(W1T @ x^T + b1)^T, grouped, shared K=1024 first ---
  GemmArgs ga1;
  for (int e = 0; e < 4; ++e) {
    ga1.d[e] = GemmDesc{w1t_sh + (size_t)e * 512 * 1024, xf_b, sh_b1 + e * 512,
                        H + (size_t)(8 + e) * 4096 * 512, 1024, 512, 8};
    ga1.d[4 + e] = GemmDesc{w1t_t1 + (size_t)e * 512 * 512, x1_b, t1_b1 + e * 512,
                            H + (size_t)e * 4096 * 512, 512, 512, 4};
    ga1.d[8 + e] = GemmDesc{w1t_t2 + (size_t)e * 512 * 512, x2_b, t2_b1 + e * 512,
                            H + (size_t)(4 + e) * 4096 * 512, 512, 512, 4};
  }
  k_gemm256<<<dim3(32, 12), 512, 0, stream>>>(ga1);

  // --- GEMM2 (flipped): Out[b][o] = relu(W2T @ H^T + b2)^T, grouped ---
  GemmArgs ga2;
  for (int e = 0; e < 12; ++e) {
    const float* bias = (e < 4) ? (t1_b2 + e * 256)
                      : (e < 8) ? (t2_b2 + (e - 4) * 256)
                                : (sh_b2 + (e - 8) * 256);
    ga2.d[e] = GemmDesc{w2t + (size_t)e * 256 * 512, H + (size_t)e * 4096 * 512, bias,
                        OutB + (size_t)e * 4096 * 256, 512, 256, 4};
  }
  k_gemm256<<<dim3(16, 12), 512, 0, stream>>>(ga2);

  // --- gated reduce -> d_out (out_sh | out1 | out2), fp32 ---
  k_reduce<<<512, 256, 0, stream>>>(OutB, gshv, g1v, g2v, (float*)d_out);
}

// Round 5
// 107.971 us; speedup vs baseline: 1.1425x; 1.1425x over previous
//
#include <hip/hip_runtime.h>

typedef unsigned short u16;
typedef __attribute__((ext_vector_type(8))) short short8;
typedef __attribute__((ext_vector_type(4))) float f32x4;

#define GL2LDS16(src, dst) __builtin_amdgcn_global_load_lds( \
    (const __attribute__((address_space(1))) void*)(src),    \
    (__attribute__((address_space(3))) void*)(dst), 16, 0, 0)

__device__ __forceinline__ u16 f2bf(float f) {
  union { float f; unsigned u; } v; v.f = f;
  unsigned r = v.u + 0x7fffu + ((v.u >> 16) & 1u);
  return (u16)(r >> 16);
}
__device__ __forceinline__ float bf2f(u16 h) {
  union { unsigned u; float f; } v; v.u = ((unsigned)h) << 16; return v.f;
}

// ---------------- gates + x->bf16 conversion, one wave per row ----------------
__global__ void k_gates_cvt(const float* __restrict__ xf, const float* __restrict__ x1,
                            const float* __restrict__ x2,
                            const float* __restrict__ gshW, const float* __restrict__ gshB,
                            const float* __restrict__ g1W, const float* __restrict__ g1B,
                            const float* __restrict__ g2W, const float* __restrict__ g2B,
                            u16* __restrict__ xfb, u16* __restrict__ x1b, u16* __restrict__ x2b,
                            float* __restrict__ gsh, float* __restrict__ g1o,
                            float* __restrict__ g2o) {
  const int b = blockIdx.x, lane = threadIdx.x;
  float s[12];
#pragma unroll
  for (int j = 0; j < 12; ++j) s[j] = 0.f;
  {
    const float* xr = xf + (size_t)b * 1024;
    u16* xw = xfb + (size_t)b * 1024;
    for (int k = lane; k < 1024; k += 64) {
      float v = xr[k];
      xw[k] = f2bf(v);
      const float* wr = gshW + (size_t)k * 12;
#pragma unroll
      for (int j = 0; j < 12; ++j) s[j] += v * wr[j];
    }
  }
  float u[8], w[8];
#pragma unroll
  for (int j = 0; j < 8; ++j) { u[j] = 0.f; w[j] = 0.f; }
  {
    const float* xr1 = x1 + (size_t)b * 512;
    const float* xr2 = x2 + (size_t)b * 512;
    u16* xw1 = x1b + (size_t)b * 512;
    u16* xw2 = x2b + (size_t)b * 512;
    for (int k = lane; k < 512; k += 64) {
      float v1 = xr1[k], v2 = xr2[k];
      xw1[k] = f2bf(v1); xw2[k] = f2bf(v2);
      const float* w1r = g1W + (size_t)k * 8;
      const float* w2r = g2W + (size_t)k * 8;
#pragma unroll
      for (int j = 0; j < 8; ++j) { u[j] += v1 * w1r[j]; w[j] += v2 * w2r[j]; }
    }
  }
#pragma unroll
  for (int off = 32; off >= 1; off >>= 1) {
#pragma unroll
    for (int j = 0; j < 12; ++j) s[j] += __shfl_xor(s[j], off, 64);
#pragma unroll
    for (int j = 0; j < 8; ++j) { u[j] += __shfl_xor(u[j], off, 64); w[j] += __shfl_xor(w[j], off, 64); }
  }
  if (lane == 0) {
    float m = -1e30f, tot = 0.f;
#pragma unroll
    for (int j = 0; j < 12; ++j) { s[j] += gshB[j]; m = fmaxf(m, s[j]); }
#pragma unroll
    for (int j = 0; j < 12; ++j) { s[j] = __expf(s[j] - m); tot += s[j]; }
    float inv = 1.f / tot;
#pragma unroll
    for (int j = 0; j < 12; ++j) gsh[(size_t)b * 12 + j] = s[j] * inv;
    m = -1e30f; tot = 0.f;
#pragma unroll
    for (int j = 0; j < 8; ++j) { u[j] += g1B[j]; m = fmaxf(m, u[j]); }
#pragma unroll
    for (int j = 0; j < 8; ++j) { u[j] = __expf(u[j] - m); tot += u[j]; }
    inv = 1.f / tot;
#pragma unroll
    for (int j = 0; j < 8; ++j) g1o[(size_t)b * 8 + j] = u[j] * inv;
    m = -1e30f; tot = 0.f;
#pragma unroll
    for (int j = 0; j < 8; ++j) { w[j] += g2B[j]; m = fmaxf(m, w[j]); }
#pragma unroll
    for (int j = 0; j < 8; ++j) { w[j] = __expf(w[j] - m); tot += w[j]; }
    inv = 1.f / tot;
#pragma unroll
    for (int j = 0; j < 8; ++j) g2o[(size_t)b * 8 + j] = w[j] * inv;
  }
}

// ------------- merged weight transpose+convert: fp32 [z][R][C] -> bf16 [z][C][R] -------------
struct TD { const float* src; u16* dst; int lgTps; int lgNtx; int R; int C; int tileBase; };
struct TArgs { TD d[6]; };

__global__ void k_transpose_all(TArgs ta) {
  __shared__ float tile[32][33];
  const int x = blockIdx.x;
  int di = 0;
#pragma unroll
  for (int i = 1; i < 6; ++i)
    if (x >= ta.d[i].tileBase) di = i;
  TD d = ta.d[di];
  const int local = x - d.tileBase;
  const int slice = local >> d.lgTps;
  const int ti = local & ((1 << d.lgTps) - 1);
  const int tx = ti & ((1 << d.lgNtx) - 1);
  const int ty = ti >> d.lgNtx;
  const float* src = d.src + (size_t)slice * d.R * d.C;
  u16* dst = d.dst + (size_t)slice * d.R * d.C;
  const int c0 = tx * 32, r0 = ty * 32;
  const int ttx = threadIdx.x, tty = threadIdx.y;
#pragma unroll
  for (int i = tty; i < 32; i += 8)
    tile[i][ttx] = src[(size_t)(r0 + i) * d.C + (c0 + ttx)];
  __syncthreads();
#pragma unroll
  for (int i = tty; i < 32; i += 8)
    dst[(size_t)(c0 + i) * d.R + (r0 + ttx)] = f2bf(tile[ttx][i]);
}

// ---------- grouped GEMM, TLP structure: C = relu(A @ B^T + bias), bf16 in/out ----------
// A: [4096][K] bf16 (batch rows); BT: [N][K] bf16 (weights); C: [4096][N] bf16.
// BM=128, BN=256, BK=32, 8 waves (2M x 4N), wave tile 64x64, acc[4][4] (64 VGPR).
// __launch_bounds__(512,4) -> <=128 VGPR -> 4 waves/SIMD -> 2 blocks/CU (LDS 48KB).
// Double-buffered BK=32 tiles; 2 phases/tile; ONE barrier per tile (hazard-audited);
// stage(t+1) issued in P0, drained by per-wave vmcnt(0) before the tile barrier.
// Swizzle both-sides: 16B-chunk ^= (row&3)  -> 2-way bank aliasing = free.
struct GemmDesc {
  const u16* A;
  const u16* BT;
  const float* bias;
  u16* C;
  int K;
  int N;
  int T;  // K/32
};
struct GemmArgs { GemmDesc d[12]; };

#define BARR __builtin_amdgcn_s_barrier()
#define WAITL0                                                   \
  {                                                              \
    asm volatile("s_waitcnt lgkmcnt(0)" ::: "memory");           \
    __builtin_amdgcn_sched_barrier(0);                           \
  }
#define WAITV0 asm volatile("s_waitcnt vmcnt(0)" ::: "memory")

__global__ __launch_bounds__(512, 4) void k_gemm128(GemmArgs args) {
  __shared__ __align__(16) u16 As[2 * 128 * 32];  // 16 KB
  __shared__ __align__(16) u16 Bs[2 * 256 * 32];  // 32 KB

  GemmDesc g = args.d[blockIdx.y];
  const int K = g.K, N = g.N, T = g.T;
  const int ntN = N >> 8;  // 2 (N=512) or 1 (N=256)
  const int bx = blockIdx.x;
  const int nt = bx & (ntN - 1);
  const int bt = (ntN == 2) ? (bx >> 1) : bx;
  const int row0 = bt << 7;
  const int col0 = nt << 8;

  const int tid = threadIdx.x;
  const int lane = tid & 63;
  const int wid = tid >> 6;
  const int wm = wid & 1;    // 2 M-strips of 64
  const int wn = wid >> 1;   // 4 N-strips of 64
  const int lrow = lane & 15;
  const int lkq = lane >> 4;  // 0..3

  // ds_read byte offsets within one buffer (row*64B + swizzled 16B chunk)
  const int csw = (lkq ^ (lrow & 3)) * 16;
  int aoff[4], boff[4];
#pragma unroll
  for (int mi = 0; mi < 4; ++mi) aoff[mi] = (wm * 64 + mi * 16 + lrow) * 64 + csw;
#pragma unroll
  for (int ni = 0; ni < 4; ++ni) boff[ni] = (wn * 64 + ni * 16 + lrow) * 64 + csw;

  // staging: linear LDS dest (chunk = tid [+512 for B's 2nd half]), pre-swizzled global src
  const int ar = tid >> 2;                    // 0..127
  const int acs = (tid & 3) ^ (ar & 3);
  const u16* aSrc = g.A + (size_t)(row0 + ar) * K + acs * 8;
  const int br0 = tid >> 2;                   // 0..127
  const int bc0 = (tid & 3) ^ (br0 & 3);
  const u16* bSrc0 = g.BT + (size_t)(col0 + br0) * K + bc0 * 8;
  const int br1 = 128 + (tid >> 2);           // 128..255
  const int bc1 = (tid & 3) ^ (br1 & 3);
  const u16* bSrc1 = g.BT + (size_t)(col0 + br1) * K + bc1 * 8;

  auto STAGE = [&](int buf, int t) {
    GL2LDS16(aSrc + (size_t)t * 32, &As[buf * 4096 + tid * 8]);
    GL2LDS16(bSrc0 + (size_t)t * 32, &Bs[buf * 8192 + tid * 8]);
    GL2LDS16(bSrc1 + (size_t)t * 32, &Bs[buf * 8192 + 4096 + tid * 8]);
  };

  f32x4 acc[4][4];
#pragma unroll
  for (int m = 0; m < 4; ++m)
#pragma unroll
    for (int n = 0; n < 4; ++n)
      acc[m][n] = (f32x4){0.f, 0.f, 0.f, 0.f};

  STAGE(0, 0);
  WAITV0;
  BARR;

  for (int t = 0; t < T; ++t) {
    const int buf = t & 1;
    const char* Ab = (const char*)As + buf * 8192;
    const char* Bb = (const char*)Bs + buf * 16384;
    short8 a0, a1, b[4];
    // P0: B + A(mi0,1) reads, stage next tile, then 8 MFMA
#pragma unroll
    for (int ni = 0; ni < 4; ++ni) b[ni] = *(const short8*)(Bb + boff[ni]);
    a0 = *(const short8*)(Ab + aoff[0]);
    a1 = *(const short8*)(Ab + aoff[1]);
    if (t + 1 < T) STAGE(buf ^ 1, t + 1);
    WAITL0;
    __builtin_amdgcn_s_setprio(1);
#pragma unroll
    for (int ni = 0; ni < 4; ++ni) {
      acc[0][ni] = __builtin_amdgcn_mfma_f32_16x16x32_bf16(a0, b[ni], acc[0][ni], 0, 0, 0);
      acc[1][ni] = __builtin_amdgcn_mfma_f32_16x16x32_bf16(a1, b[ni], acc[1][ni], 0, 0, 0);
    }
    __builtin_amdgcn_s_setprio(0);
    // P1: A(mi2,3) reads, 8 MFMA, then drain stage + tile barrier
    a0 = *(const short8*)(Ab + aoff[2]);
    a1 = *(const short8*)(Ab + aoff[3]);
    WAITL0;
    __builtin_amdgcn_s_setprio(1);
#pragma unroll
    for (int ni = 0; ni < 4; ++ni) {
      acc[2][ni] = __builtin_amdgcn_mfma_f32_16x16x32_bf16(a0, b[ni], acc[2][ni], 0, 0, 0);
      acc[3][ni] = __builtin_amdgcn_mfma_f32_16x16x32_bf16(a1, b[ni], acc[3][ni], 0, 0, 0);
    }
    __builtin_amdgcn_s_setprio(0);
    WAITV0;
    BARR;
  }

  // epilogue: bias + relu + bf16 store. C/D map: col=lane&15, row=lkq*4+j
#pragma unroll
  for (int ni = 0; ni < 4; ++ni) {
    const int gc = col0 + wn * 64 + ni * 16 + lrow;
    const float bv = g.bias[gc];
#pragma unroll
    for (int mi = 0; mi < 4; ++mi) {
      const int gr = row0 + wm * 64 + mi * 16 + lkq * 4;
#pragma unroll
      for (int j = 0; j < 4; ++j) {
        float o = fmaxf(acc[mi][ni][j] + bv, 0.f);
        g.C[(size_t)(gr + j) * N + gc] = f2bf(o);
      }
    }
  }
}

// ---------------- gated reduce: 3 outputs from 12 expert outputs ----------------
__global__ void k_reduce(const u16* __restrict__ OutB, const float* __restrict__ gsh,
                         const float* __restrict__ g1, const float* __restrict__ g2,
                         float* __restrict__ out) {
  int t = blockIdx.x * 256 + threadIdx.x;
  int b = t >> 5;
  int c0 = (t & 31) << 3;
  float wsh[12], w1[8], w2[8];
#pragma unroll
  for (int j = 0; j < 12; ++j) wsh[j] = gsh[(size_t)b * 12 + j];
#pragma unroll
  for (int j = 0; j < 8; ++j) { w1[j] = g1[(size_t)b * 8 + j]; w2[j] = g2[(size_t)b * 8 + j]; }
  float ash[8] = {0, 0, 0, 0, 0, 0, 0, 0};
  float a1[8] = {0, 0, 0, 0, 0, 0, 0, 0};
  float a2[8] = {0, 0, 0, 0, 0, 0, 0, 0};
#pragma unroll
  for (int e = 0; e < 12; ++e) {
    short8 v = *(const short8*)&OutB[((size_t)e * 4096 + b) * 256 + c0];
    float f[8];
#pragma unroll
    for (int i = 0; i < 8; ++i) f[i] = bf2f((u16)v[i]);
#pragma unroll
    for (int i = 0; i < 8; ++i) ash[i] += wsh[e] * f[i];
    if (e < 4) {
#pragma unroll
      for (int i = 0; i < 8; ++i) a1[i] += w1[e] * f[i];
    } else if (e < 8) {
#pragma unroll
      for (int i = 0; i < 8; ++i) a2[i] += w2[e - 4] * f[i];
    } else {
#pragma unroll
      for (int i = 0; i < 8; ++i) a1[i] += w1[e - 4] * f[i];
#pragma unroll
      for (int i = 0; i < 8; ++i) a2[i] += w2[e - 4] * f[i];
    }
  }
  size_t base = (size_t)b * 256 + c0;
  float4* o;
  o = (float4*)(out + base);
  o[0] = make_float4(ash[0], ash[1], ash[2], ash[3]);
  o[1] = make_float4(ash[4], ash[5], ash[6], ash[7]);
  o = (float4*)(out + 4096ull * 256 + base);
  o[0] = make_float4(a1[0], a1[1], a1[2], a1[3]);
  o[1] = make_float4(a1[4], a1[5], a1[6], a1[7]);
  o = (float4*)(out + 2ull * 4096 * 256 + base);
  o[0] = make_float4(a2[0], a2[1], a2[2], a2[3]);
  o[1] = make_float4(a2[4], a2[5], a2[6], a2[7]);
}

extern "C" void kernel_launch(void* const* d_in, const int* in_sizes, int n_in,
                              void* d_out, int out_size, void* d_ws, size_t ws_size,
                              hipStream_t stream) {
  const float* x_full = (const float*)d_in[0];
  const float* x_t1 = (const float*)d_in[1];
  const float* x_t2 = (const float*)d_in[2];
  const float* sh_W1 = (const float*)d_in[3];
  const float* sh_b1 = (const float*)d_in[4];
  const float* sh_W2 = (const float*)d_in[5];
  const float* sh_b2 = (const float*)d_in[6];
  const float* t1_W1 = (const float*)d_in[7];
  const float* t1_b1 = (const float*)d_in[8];
  const float* t1_W2 = (const float*)d_in[9];
  const float* t1_b2 = (const float*)d_in[10];
  const float* t2_W1 = (const float*)d_in[11];
  const float* t2_b1 = (const float*)d_in[12];
  const float* t2_W2 = (const float*)d_in[13];
  const float* t2_b2 = (const float*)d_in[14];
  const float* gsh_W = (const float*)d_in[15];
  const float* gsh_b = (const float*)d_in[16];
  const float* g1_W = (const float*)d_in[17];
  const float* g1_b = (const float*)d_in[18];
  const float* g2_W = (const float*)d_in[19];
  const float* g2_b = (const float*)d_in[20];

  char* ws = (char*)d_ws;
  size_t off = 0;
  auto alloc = [&](size_t bytes) -> void* {
    void* p = ws + off;
    off += (bytes + 255) & ~(size_t)255;
    return p;
  };
  u16* xf_b = (u16*)alloc(4096ull * 1024 * 2);
  u16* x1_b = (u16*)alloc(4096ull * 512 * 2);
  u16* x2_b = (u16*)alloc(4096ull * 512 * 2);
  u16* w1t_t1 = (u16*)alloc(4ull * 512 * 512 * 2);   // [e][HID=512][K=512]
  u16* w1t_t2 = (u16*)alloc(4ull * 512 * 512 * 2);
  u16* w1t_sh = (u16*)alloc(4ull * 512 * 1024 * 2);  // [e][512][1024]
  u16* w2t = (u16*)alloc(12ull * 256 * 512 * 2);     // [slot][OUT=256][HID=512]
  u16* H = (u16*)alloc(12ull * 4096 * 512 * 2);      // hidden [slot][4096][512]
  u16* OutB = (u16*)alloc(12ull * 4096 * 256 * 2);   // expert outputs [slot][4096][256]
  float* gshv = (float*)alloc(4096ull * 12 * 4);
  float* g1v = (float*)alloc(4096ull * 8 * 4);
  float* g2v = (float*)alloc(4096ull * 8 * 4);

  // --- gates + x->bf16 (fused) ---
  k_gates_cvt<<<4096, 64, 0, stream>>>(x_full, x_t1, x_t2, gsh_W, gsh_b, g1_W, g1_b, g2_W, g2_b,
                                       xf_b, x1_b, x2_b, gshv, g1v, g2v);

  // --- weight transpose+convert, single launch ---
  TArgs ta;
  ta.d[0] = TD{t1_W1, w1t_t1, 8, 4, 512, 512, 0};
  ta.d[1] = TD{t2_W1, w1t_t2, 8, 4, 512, 512, 1024};
  ta.d[2] = TD{sh_W1, w1t_sh, 9, 4, 1024, 512, 2048};
  ta.d[3] = TD{t1_W2, w2t, 7, 3, 512, 256, 4096};
  ta.d[4] = TD{t2_W2, w2t + 4ull * 256 * 512, 7, 3, 512, 256, 4608};
  ta.d[5] = TD{sh_W2, w2t + 8ull * 256 * 512, 7, 3, 512, 256, 5120};
  k_transpose_all<<<5632, dim3(32, 8), 0, stream>>>(ta);

  // --- GEMM1: H = relu(x @ W1 + b1), grouped over 12 experts (shared K=1024 first) ---
  GemmArgs ga1;
  for (int e = 0; e < 4; ++e) {
    ga1.d[e] = GemmDesc{xf_b, w1t_sh + (size_t)e * 512 * 1024, sh_b1 + e * 512,
                        H + (size_t)(8 + e) * 4096 * 512, 1024, 512, 32};
    ga1.d[4 + e] = GemmDesc{x1_b, w1t_t1 + (size_t)e * 512 * 512, t1_b1 + e * 512,
                            H + (size_t)e * 4096 * 512, 512, 512, 16};
    ga1.d[8 + e] = GemmDesc{x2_b, w1t_t2 + (size_t)e * 512 * 512, t2_b1 + e * 512,
                            H + (size_t)(4 + e) * 4096 * 512, 512, 512, 16};
  }
  k_gemm128<<<dim3(64, 12), 512, 0, stream>>>(ga1);

  // --- GEMM2: Out = relu(H @ W2 + b2), grouped over 12 experts ---
  GemmArgs ga2;
  for (int e = 0; e < 12; ++e) {
    const float* bias = (e < 4) ? (t1_b2 + e * 256)
                      : (e < 8) ? (t2_b2 + (e - 4) * 256)
                                : (sh_b2 + (e - 8) * 256);
    ga2.d[e] = GemmDesc{H + (size_t)e * 4096 * 512, w2t + (size_t)e * 256 * 512, bias,
                        OutB + (size_t)e * 4096 * 256, 512, 256, 16};
  }
  k_gemm128<<<dim3(32, 12), 512, 0, stream>>>(ga2);

  // --- gated reduce -> d_out (out_sh | out1 | out2), fp32 ---
  k_reduce<<<512, 256, 0, stream>>>(OutB, gshv, g1v, g2v, (float*)d_out);
}